// Round 2
// baseline (758.152 us; speedup 1.0000x reference)
//
#include <hip/hip_runtime.h>
#include <stdint.h>

#define BN 8
#define TN 4096
#define CN 512
#define TA 2048
#define RR 1024
#define BASEB 1024
#define MROWS 3072

// ---------------- kernel 1: inverse norms of every k row -------------------
__global__ __launch_bounds__(256) void norms_kernel(const float* __restrict__ k,
                                                    float* __restrict__ inv) {
    int row = blockIdx.x * 4 + (threadIdx.x >> 6);
    int lane = threadIdx.x & 63;
    if (row >= BN * TN) return;
    const float* p = k + (size_t)row * CN;
    float4 v1 = *(const float4*)(p + lane * 8);
    float4 v2 = *(const float4*)(p + lane * 8 + 4);
    float s = v1.x*v1.x + v1.y*v1.y + v1.z*v1.z + v1.w*v1.w
            + v2.x*v2.x + v2.y*v2.y + v2.z*v2.z + v2.w*v2.w;
    #pragma unroll
    for (int off = 32; off > 0; off >>= 1) s += __shfl_down(s, off);
    if (lane == 0) inv[row] = 1.0f / (sqrtf(s) + 1e-12f);
}

// ---------------- kernel 2: init node keys --------------------------------
// hi = ofloat(-inf) = 0x007FFFFF, lo = 0xFFFFFFFF (decodes to j = 0)
__global__ void init_kernel(unsigned long long* __restrict__ nodekey) {
    int idx = blockIdx.x * 256 + threadIdx.x;
    if (idx < BN * TA)
        nodekey[idx] = (((unsigned long long)0x007FFFFFu) << 32) | 0xFFFFFFFFull;
}

__device__ __forceinline__ unsigned ofloat(float f) {
    unsigned u = __float_as_uint(f);
    return (u & 0x80000000u) ? ~u : (u | 0x80000000u);
}

// ---------------- kernel 3: fused score GEMM + row max/argmax -------------
// grid: (32 i-tiles of 64, 4 j-chunks of 512, 8 batches), block 256 (16x16)
__global__ __launch_bounds__(256) void score_kernel(const float* __restrict__ k,
                                                    const float* __restrict__ inv,
                                                    unsigned long long* __restrict__ nodekey) {
    __shared__ float aT[32][68];
    __shared__ float bT[32][68];
    const int b  = blockIdx.z;
    const int i0 = blockIdx.x * 64;
    const int j0 = blockIdx.y * 512;
    const int tx = threadIdx.x & 15, ty = threadIdx.x >> 4;
    const float* kb = k + (size_t)b * TN * CN;
    const float* invb = inv + b * TN;

    const int trow = threadIdx.x >> 2;      // 0..63  (staging row)
    const int tkk  = (threadIdx.x & 3) * 8; // 0,8,16,24
    const float ia_st = invb[2 * (i0 + trow)];  // A staging row is fixed

    unsigned long long best[4];
    #pragma unroll
    for (int r = 0; r < 4; ++r) best[r] = 0ull;

    for (int jt = 0; jt < 8; ++jt) {
        const int jrow = j0 + jt * 64 + trow;
        const float ib_st = invb[2 * jrow + 1];
        float acc[4][4] = {{0.f}};
        for (int kt = 0; kt < CN; kt += 32) {
            const float* ga = kb + (size_t)(2 * (i0 + trow)) * CN + kt + tkk;
            const float* gb = kb + (size_t)(2 * jrow + 1) * CN + kt + tkk;
            float4 a1 = *(const float4*)ga;
            float4 a2 = *(const float4*)(ga + 4);
            float4 b1 = *(const float4*)gb;
            float4 b2 = *(const float4*)(gb + 4);
            __syncthreads();
            // stage NORMALIZED values (matches reference's normalize-then-dot)
            aT[tkk+0][trow]=a1.x*ia_st; aT[tkk+1][trow]=a1.y*ia_st;
            aT[tkk+2][trow]=a1.z*ia_st; aT[tkk+3][trow]=a1.w*ia_st;
            aT[tkk+4][trow]=a2.x*ia_st; aT[tkk+5][trow]=a2.y*ia_st;
            aT[tkk+6][trow]=a2.z*ia_st; aT[tkk+7][trow]=a2.w*ia_st;
            bT[tkk+0][trow]=b1.x*ib_st; bT[tkk+1][trow]=b1.y*ib_st;
            bT[tkk+2][trow]=b1.z*ib_st; bT[tkk+3][trow]=b1.w*ib_st;
            bT[tkk+4][trow]=b2.x*ib_st; bT[tkk+5][trow]=b2.y*ib_st;
            bT[tkk+6][trow]=b2.z*ib_st; bT[tkk+7][trow]=b2.w*ib_st;
            __syncthreads();
            #pragma unroll
            for (int kk = 0; kk < 32; ++kk) {
                float ar[4], br[4];
                *(float4*)ar = *(const float4*)&aT[kk][ty * 4];
                *(float4*)br = *(const float4*)&bT[kk][tx * 4];
                #pragma unroll
                for (int r = 0; r < 4; ++r)
                    #pragma unroll
                    for (int c = 0; c < 4; ++c)
                        acc[r][c] += ar[r] * br[c];
            }
        }
        // epilogue: track best (value, smallest j on tie)
        #pragma unroll
        for (int c = 0; c < 4; ++c) {
            int j = j0 + jt * 64 + tx * 4 + c;
            #pragma unroll
            for (int r = 0; r < 4; ++r) {
                float sc = acc[r][c];
                unsigned long long key =
                    (((unsigned long long)ofloat(sc)) << 32) | (0xFFFFFFFFu - (unsigned)j);
                if (key > best[r]) best[r] = key;
            }
        }
    }
    // reduce across the 16 tx lanes via 32-bit shuffles only, then atomic
    #pragma unroll
    for (int r = 0; r < 4; ++r) {
        unsigned hi = (unsigned)(best[r] >> 32);
        unsigned lo = (unsigned)best[r];
        #pragma unroll
        for (int m = 8; m > 0; m >>= 1) {
            unsigned ohi = (unsigned)__shfl_xor((int)hi, m, 16);
            unsigned olo = (unsigned)__shfl_xor((int)lo, m, 16);
            if (ohi > hi || (ohi == hi && olo > lo)) { hi = ohi; lo = olo; }
        }
        if (tx == 0) {
            int i = i0 + ty * 4 + r;
            if (i != 0) {  // PROTECT_CLS: i==0 stays -inf
                unsigned long long key = (((unsigned long long)hi) << 32) | lo;
                atomicMax(&nodekey[b * TA + i], key);
            }
        }
    }
}

// ---------------- kernel 4: per-batch rank by counting --------------------
// one block (1024 thr) per batch. K_i = (hi<<32)|(2047-i): descending max,
// tie -> smaller i ranks earlier (matches stable argsort of -node_max).
__global__ __launch_bounds__(1024) void rank_kernel(const unsigned long long* __restrict__ nodekey,
                                                    int* __restrict__ is_src,
                                                    int* __restrict__ unm_rank) {
    __shared__ unsigned long long K[2048];
    __shared__ unsigned char flag[2048];  // 1 = merged (src)
    const int b = blockIdx.x;
    const int t = threadIdx.x;

    for (int i = t; i < 2048; i += 1024) {
        unsigned hi = (unsigned)(nodekey[b * TA + i] >> 32);
        K[i] = (((unsigned long long)hi) << 32) | (unsigned)(2047 - i);
    }
    __syncthreads();
    for (int i = t; i < 2048; i += 1024) {
        unsigned long long ki = K[i];
        int rank = 0;
        for (int j = 0; j < 2048; ++j) rank += (K[j] > ki) ? 1 : 0;
        flag[i] = (rank < RR) ? 1 : 0;   // top-RR node_max are merged
    }
    __syncthreads();
    for (int i = t; i < 2048; i += 1024) {
        int cnt = 0;
        for (int j = 0; j < i; ++j) cnt += flag[j] ? 0 : 1;
        is_src[b * TA + i] = flag[i];
        unm_rank[b * TA + i] = cnt;      // # unmerged with index < i
    }
}

// ---------------- kernel 5: copy unmerged + dst base rows -----------------
__global__ __launch_bounds__(128) void copy_kernel(const float* __restrict__ x,
                                                   const int* __restrict__ is_src,
                                                   const int* __restrict__ unm_rank,
                                                   float* __restrict__ out) {
    const int b = blockIdx.y;
    const int tt = blockIdx.x;
    const float* src;
    float* dst;
    if (tt < 2048) {
        int i = tt;
        if (is_src[b * TA + i]) return;
        src = x + ((size_t)b * TN + 2 * i) * CN;
        dst = out + ((size_t)b * MROWS + unm_rank[b * TA + i]) * CN;
    } else {
        int j = tt - 2048;
        src = x + ((size_t)b * TN + 2 * j + 1) * CN;
        dst = out + ((size_t)b * MROWS + BASEB + j) * CN;
    }
    ((float4*)dst)[threadIdx.x] = ((const float4*)src)[threadIdx.x];
}

// ---------------- kernel 6: scatter-add merged sources into dst rows ------
__global__ __launch_bounds__(256) void scatter_kernel(const float* __restrict__ x,
                                                      const int* __restrict__ is_src,
                                                      const unsigned long long* __restrict__ nodekey,
                                                      float* __restrict__ out) {
    const int b = blockIdx.y;
    const int i = blockIdx.x;
    if (!is_src[b * TA + i]) return;
    unsigned j = 0xFFFFFFFFu - (unsigned)(nodekey[b * TA + i] & 0xFFFFFFFFull);
    const float* src = x + ((size_t)b * TN + 2 * i) * CN;
    float* dst = out + ((size_t)b * MROWS + BASEB + j) * CN;
    for (int c = threadIdx.x; c < CN; c += 256) atomicAdd(&dst[c], src[c]);
}

// ---------------- kernel 7: source_index (written as float) ---------------
__global__ __launch_bounds__(256) void si_kernel(const int* __restrict__ is_src,
                                                 const int* __restrict__ unm_rank,
                                                 const unsigned long long* __restrict__ nodekey,
                                                 float* __restrict__ out_si) {
    int idx = blockIdx.x * 256 + threadIdx.x;
    if (idx >= BN * TN) return;
    int b = idx / TN, tt = idx % TN;
    int val;
    if (tt & 1) {
        val = BASEB + (tt >> 1);
    } else {
        int i = tt >> 1;
        if (is_src[b * TA + i]) {
            unsigned j = 0xFFFFFFFFu - (unsigned)(nodekey[b * TA + i] & 0xFFFFFFFFull);
            val = BASEB + (int)j;
        } else {
            val = unm_rank[b * TA + i];
        }
    }
    out_si[idx] = (float)val;
}

extern "C" void kernel_launch(void* const* d_in, const int* in_sizes, int n_in,
                              void* d_out, int out_size, void* d_ws, size_t ws_size,
                              hipStream_t stream) {
    const float* x = (const float*)d_in[0];
    const float* k = (const float*)d_in[1];
    float* out = (float*)d_out;
    float* out_si = out + (size_t)BN * MROWS * CN;

    char* ws = (char*)d_ws;
    float* inv                  = (float*)(ws);                          // 128 KB
    unsigned long long* nodekey = (unsigned long long*)(ws + 256 * 1024); // 128 KB
    int* is_src                 = (int*)(ws + 384 * 1024);               // 64 KB
    int* unm_rank               = (int*)(ws + 448 * 1024);               // 64 KB

    norms_kernel<<<dim3(BN * TN / 4), dim3(256), 0, stream>>>(k, inv);
    init_kernel<<<dim3((BN * TA + 255) / 256), dim3(256), 0, stream>>>(nodekey);
    score_kernel<<<dim3(32, 4, BN), dim3(256), 0, stream>>>(k, inv, nodekey);
    rank_kernel<<<dim3(BN), dim3(1024), 0, stream>>>(nodekey, is_src, unm_rank);
    copy_kernel<<<dim3(4096, BN), dim3(128), 0, stream>>>(x, is_src, unm_rank, out);
    scatter_kernel<<<dim3(2048, BN), dim3(256), 0, stream>>>(x, is_src, nodekey, out);
    si_kernel<<<dim3((BN * TN + 255) / 256), dim3(256), 0, stream>>>(is_src, unm_rank, nodekey, out_si);
}

// Round 3
// 600.755 us; speedup vs baseline: 1.2620x; 1.2620x over previous
//
#include <hip/hip_runtime.h>
#include <stdint.h>

#define BN 8
#define TN 4096
#define CN 512
#define TA 2048
#define RR 1024
#define BASEB 1024
#define MROWS 3072

typedef _Float16 f16x8 __attribute__((ext_vector_type(8)));
typedef float f32x4 __attribute__((ext_vector_type(4)));

__device__ __forceinline__ unsigned ofloat(float f) {
    unsigned u = __float_as_uint(f);
    return (u & 0x80000000u) ? ~u : (u | 0x80000000u);
}

// ---------- kernel 1: normalize rows of k, split into H(x2^10)/L fp16 planes,
// ---------- deinterleave even rows -> A planes, odd rows -> B planes
__global__ __launch_bounds__(256) void split_kernel(const float* __restrict__ k,
        _Float16* __restrict__ Ahi, _Float16* __restrict__ Alo,
        _Float16* __restrict__ Bhi, _Float16* __restrict__ Blo) {
    int row = blockIdx.x * 4 + (threadIdx.x >> 6);
    int lane = threadIdx.x & 63;
    const float* p = k + (size_t)row * CN;
    float4 v1 = *(const float4*)(p + lane * 8);
    float4 v2 = *(const float4*)(p + lane * 8 + 4);
    float s = v1.x*v1.x + v1.y*v1.y + v1.z*v1.z + v1.w*v1.w
            + v2.x*v2.x + v2.y*v2.y + v2.z*v2.z + v2.w*v2.w;
    #pragma unroll
    for (int off = 32; off > 0; off >>= 1) s += __shfl_xor(s, off);
    float sc = 1024.0f / (sqrtf(s) + 1e-12f);
    float m[8] = {v1.x*sc, v1.y*sc, v1.z*sc, v1.w*sc,
                  v2.x*sc, v2.y*sc, v2.z*sc, v2.w*sc};
    f16x8 H, L;
    #pragma unroll
    for (int jj = 0; jj < 8; ++jj) {
        _Float16 h = (_Float16)m[jj];
        H[jj] = h;
        L[jj] = (_Float16)(m[jj] - (float)h);
    }
    int b = row >> 12;         // row / 4096
    int tt = row & 4095;
    size_t dst = ((size_t)(b * TA + (tt >> 1))) * CN + lane * 8;
    if (tt & 1) { *(f16x8*)(Bhi + dst) = H; *(f16x8*)(Blo + dst) = L; }
    else        { *(f16x8*)(Ahi + dst) = H; *(f16x8*)(Alo + dst) = L; }
}

// ---------- kernel 2: init node keys (hi = ofloat(-inf), lo decodes to j=0)
__global__ void init_kernel(unsigned long long* __restrict__ nodekey) {
    int idx = blockIdx.x * 256 + threadIdx.x;
    if (idx < BN * TA)
        nodekey[idx] = (((unsigned long long)0x007FFFFFu) << 32) | 0xFFFFFFFFull;
}

// ---------- kernel 3: fp16-split MFMA score GEMM + fused row max/argmax ----
// grid (16 i-tiles, 16 j-tiles, 8 batches), 256 thr = 4 waves, 128x128 tile
__global__ __launch_bounds__(256) void score_mfma_kernel(
        const _Float16* __restrict__ Ahi, const _Float16* __restrict__ Alo,
        const _Float16* __restrict__ Bhi, const _Float16* __restrict__ Blo,
        unsigned long long* __restrict__ nodekey) {
    __shared__ _Float16 lds[4 * 128 * 40];   // 4 planes, padded stride 40
    const int b  = blockIdx.z;
    const int i0 = blockIdx.x * 128;
    const int j0 = blockIdx.y * 128;
    const int tid = threadIdx.x;
    const int lane = tid & 63;
    const int wid = tid >> 6;
    const int wr = (wid >> 1) * 64;
    const int wc = (wid & 1) * 64;
    const size_t boff = (size_t)b * TA * CN;

    f32x4 acc[4][4];
    #pragma unroll
    for (int m = 0; m < 4; ++m)
        #pragma unroll
        for (int n = 0; n < 4; ++n) acc[m][n] = (f32x4){0.f, 0.f, 0.f, 0.f};

    const int fr = lane & 15, ks = lane >> 4;

    for (int kt = 0; kt < CN; kt += 32) {
        // ---- stage: 8 x 16B per thread, plane = s2>>1 (compile-time) ----
        uint4 vt[8];
        #pragma unroll
        for (int s2 = 0; s2 < 8; ++s2) {
            const int cc = ((s2 & 1) << 8) + tid;     // 0..511 within plane
            const int row = cc >> 2, seg = cc & 3;
            const _Float16* gp;
            if      (s2 < 2) gp = Ahi + boff + (size_t)(i0 + row) * CN;
            else if (s2 < 4) gp = Alo + boff + (size_t)(i0 + row) * CN;
            else if (s2 < 6) gp = Bhi + boff + (size_t)(j0 + row) * CN;
            else             gp = Blo + boff + (size_t)(j0 + row) * CN;
            vt[s2] = *(const uint4*)(gp + kt + seg * 8);
        }
        __syncthreads();   // previous chunk's frag reads complete
        #pragma unroll
        for (int s2 = 0; s2 < 8; ++s2) {
            const int pl = s2 >> 1;
            const int cc = ((s2 & 1) << 8) + tid;
            const int row = cc >> 2, seg = cc & 3;
            *(uint4*)(&lds[pl * 5120 + row * 40 + seg * 8]) = vt[s2];
        }
        __syncthreads();
        // ---- fragments + 48 MFMA ----
        f16x8 bh[4], bl[4];
        #pragma unroll
        for (int n = 0; n < 4; ++n) {
            const int rrow = wc + n * 16 + fr;
            bh[n] = *(const f16x8*)(&lds[2 * 5120 + rrow * 40 + ks * 8]);
            bl[n] = *(const f16x8*)(&lds[3 * 5120 + rrow * 40 + ks * 8]);
        }
        #pragma unroll
        for (int m = 0; m < 4; ++m) {
            const int arow = wr + m * 16 + fr;
            f16x8 ah = *(const f16x8*)(&lds[0 * 5120 + arow * 40 + ks * 8]);
            f16x8 al = *(const f16x8*)(&lds[1 * 5120 + arow * 40 + ks * 8]);
            #pragma unroll
            for (int n = 0; n < 4; ++n) {
                acc[m][n] = __builtin_amdgcn_mfma_f32_16x16x32_f16(ah, bh[n], acc[m][n], 0, 0, 0);
                acc[m][n] = __builtin_amdgcn_mfma_f32_16x16x32_f16(ah, bl[n], acc[m][n], 0, 0, 0);
                acc[m][n] = __builtin_amdgcn_mfma_f32_16x16x32_f16(al, bh[n], acc[m][n], 0, 0, 0);
            }
        }
    }

    // ---- epilogue: per-row max/argmax, C/D layout col=lane&15, row=(lane>>4)*4+reg
    const float SC = 1.0f / 1048576.0f;   // 2^-20
    #pragma unroll
    for (int m = 0; m < 4; ++m) {
        #pragma unroll
        for (int reg = 0; reg < 4; ++reg) {
            unsigned bhi = 0u, blo2 = 0u;
            #pragma unroll
            for (int n = 0; n < 4; ++n) {
                float sc = acc[m][n][reg] * SC;
                unsigned j = (unsigned)(j0 + wc + n * 16 + fr);
                unsigned khi = ofloat(sc), klo = 0xFFFFFFFFu - j;
                if (khi > bhi || (khi == bhi && klo > blo2)) { bhi = khi; blo2 = klo; }
            }
            #pragma unroll
            for (int mm2 = 8; mm2 > 0; mm2 >>= 1) {
                unsigned ohi = (unsigned)__shfl_xor((int)bhi, mm2, 16);
                unsigned olo = (unsigned)__shfl_xor((int)blo2, mm2, 16);
                if (ohi > bhi || (ohi == bhi && olo > blo2)) { bhi = ohi; blo2 = olo; }
            }
            if (fr == 0) {
                int i = i0 + wr + m * 16 + ks * 4 + reg;
                if (i != 0) {   // PROTECT_CLS: i==0 stays -inf
                    unsigned long long key = (((unsigned long long)bhi) << 32) | blo2;
                    atomicMax(&nodekey[b * TA + i], key);
                }
            }
        }
    }
}

// ---------- kernel 4: per-batch rank by counting (proven) ------------------
__global__ __launch_bounds__(1024) void rank_kernel(const unsigned long long* __restrict__ nodekey,
                                                    int* __restrict__ is_src,
                                                    int* __restrict__ unm_rank) {
    __shared__ unsigned long long K[2048];
    __shared__ unsigned char flag[2048];
    const int b = blockIdx.x;
    const int t = threadIdx.x;
    for (int i = t; i < 2048; i += 1024) {
        unsigned hi = (unsigned)(nodekey[b * TA + i] >> 32);
        K[i] = (((unsigned long long)hi) << 32) | (unsigned)(2047 - i);
    }
    __syncthreads();
    for (int i = t; i < 2048; i += 1024) {
        unsigned long long ki = K[i];
        int rank = 0;
        for (int j = 0; j < 2048; ++j) rank += (K[j] > ki) ? 1 : 0;
        flag[i] = (rank < RR) ? 1 : 0;
    }
    __syncthreads();
    for (int i = t; i < 2048; i += 1024) {
        int cnt = 0;
        for (int j = 0; j < i; ++j) cnt += flag[j] ? 0 : 1;
        is_src[b * TA + i] = flag[i];
        unm_rank[b * TA + i] = cnt;
    }
}

// ---------- kernel 5: copy unmerged + dst base rows (proven) ---------------
__global__ __launch_bounds__(128) void copy_kernel(const float* __restrict__ x,
                                                   const int* __restrict__ is_src,
                                                   const int* __restrict__ unm_rank,
                                                   float* __restrict__ out) {
    const int b = blockIdx.y;
    const int tt = blockIdx.x;
    const float* src;
    float* dst;
    if (tt < 2048) {
        int i = tt;
        if (is_src[b * TA + i]) return;
        src = x + ((size_t)b * TN + 2 * i) * CN;
        dst = out + ((size_t)b * MROWS + unm_rank[b * TA + i]) * CN;
    } else {
        int j = tt - 2048;
        src = x + ((size_t)b * TN + 2 * j + 1) * CN;
        dst = out + ((size_t)b * MROWS + BASEB + j) * CN;
    }
    ((float4*)dst)[threadIdx.x] = ((const float4*)src)[threadIdx.x];
}

// ---------- kernel 6: scatter-add merged sources (proven) ------------------
__global__ __launch_bounds__(256) void scatter_kernel(const float* __restrict__ x,
                                                      const int* __restrict__ is_src,
                                                      const unsigned long long* __restrict__ nodekey,
                                                      float* __restrict__ out) {
    const int b = blockIdx.y;
    const int i = blockIdx.x;
    if (!is_src[b * TA + i]) return;
    unsigned j = 0xFFFFFFFFu - (unsigned)(nodekey[b * TA + i] & 0xFFFFFFFFull);
    const float* src = x + ((size_t)b * TN + 2 * i) * CN;
    float* dst = out + ((size_t)b * MROWS + BASEB + j) * CN;
    for (int c = threadIdx.x; c < CN; c += 256) atomicAdd(&dst[c], src[c]);
}

// ---------- kernel 7: source_index (proven) --------------------------------
__global__ __launch_bounds__(256) void si_kernel(const int* __restrict__ is_src,
                                                 const int* __restrict__ unm_rank,
                                                 const unsigned long long* __restrict__ nodekey,
                                                 float* __restrict__ out_si) {
    int idx = blockIdx.x * 256 + threadIdx.x;
    if (idx >= BN * TN) return;
    int b = idx / TN, tt = idx % TN;
    int val;
    if (tt & 1) {
        val = BASEB + (tt >> 1);
    } else {
        int i = tt >> 1;
        if (is_src[b * TA + i]) {
            unsigned j = 0xFFFFFFFFu - (unsigned)(nodekey[b * TA + i] & 0xFFFFFFFFull);
            val = BASEB + (int)j;
        } else {
            val = unm_rank[b * TA + i];
        }
    }
    out_si[idx] = (float)val;
}

extern "C" void kernel_launch(void* const* d_in, const int* in_sizes, int n_in,
                              void* d_out, int out_size, void* d_ws, size_t ws_size,
                              hipStream_t stream) {
    const float* x = (const float*)d_in[0];
    const float* k = (const float*)d_in[1];
    float* out = (float*)d_out;
    float* out_si = out + (size_t)BN * MROWS * CN;

    char* ws = (char*)d_ws;
    const size_t PLANE = (size_t)BN * TA * CN;          // 8,388,608 elements
    _Float16* Ahi = (_Float16*)ws;
    _Float16* Alo = Ahi + PLANE;
    _Float16* Bhi = Alo + PLANE;
    _Float16* Blo = Bhi + PLANE;
    char* tail = ws + 4 * PLANE * sizeof(_Float16);     // 64 MB
    unsigned long long* nodekey = (unsigned long long*)(tail);
    int* is_src   = (int*)(tail + 128 * 1024);
    int* unm_rank = (int*)(tail + 192 * 1024);

    split_kernel<<<dim3(BN * TN / 4), dim3(256), 0, stream>>>(k, Ahi, Alo, Bhi, Blo);
    init_kernel<<<dim3((BN * TA + 255) / 256), dim3(256), 0, stream>>>(nodekey);
    score_mfma_kernel<<<dim3(16, 16, BN), dim3(256), 0, stream>>>(Ahi, Alo, Bhi, Blo, nodekey);
    rank_kernel<<<dim3(BN), dim3(1024), 0, stream>>>(nodekey, is_src, unm_rank);
    copy_kernel<<<dim3(4096, BN), dim3(128), 0, stream>>>(x, is_src, unm_rank, out);
    scatter_kernel<<<dim3(2048, BN), dim3(256), 0, stream>>>(x, is_src, nodekey, out);
    si_kernel<<<dim3((BN * TN + 255) / 256), dim3(256), 0, stream>>>(is_src, unm_rank, nodekey, out_si);
}

// Round 4
// 387.937 us; speedup vs baseline: 1.9543x; 1.5486x over previous
//
#include <hip/hip_runtime.h>
#include <stdint.h>

#define BN 8
#define TN 4096
#define CN 512
#define TA 2048
#define RR 1024
#define BASEB 1024
#define MROWS 3072
#define KC 32

typedef _Float16 f16x8 __attribute__((ext_vector_type(8)));
typedef float f32x4 __attribute__((ext_vector_type(4)));
typedef __attribute__((address_space(3))) uint32_t lds_u32_t;
typedef __attribute__((address_space(1))) const uint32_t g_u32_t;

__device__ __forceinline__ unsigned ofloat(float f) {
    unsigned u = __float_as_uint(f);
    return (u & 0x80000000u) ? ~u : (u | 0x80000000u);
}

// ---------- kernel 1: normalize rows of k, split into H(x2^10)/L fp16 planes,
// ---------- deinterleave even rows -> A planes, odd rows -> B planes
__global__ __launch_bounds__(256) void split_kernel(const float* __restrict__ k,
        _Float16* __restrict__ Ahi, _Float16* __restrict__ Alo,
        _Float16* __restrict__ Bhi, _Float16* __restrict__ Blo) {
    int row = blockIdx.x * 4 + (threadIdx.x >> 6);
    int lane = threadIdx.x & 63;
    const float* p = k + (size_t)row * CN;
    float4 v1 = *(const float4*)(p + lane * 8);
    float4 v2 = *(const float4*)(p + lane * 8 + 4);
    float s = v1.x*v1.x + v1.y*v1.y + v1.z*v1.z + v1.w*v1.w
            + v2.x*v2.x + v2.y*v2.y + v2.z*v2.z + v2.w*v2.w;
    #pragma unroll
    for (int off = 32; off > 0; off >>= 1) s += __shfl_xor(s, off);
    float sc = 1024.0f / (sqrtf(s) + 1e-12f);
    float m[8] = {v1.x*sc, v1.y*sc, v1.z*sc, v1.w*sc,
                  v2.x*sc, v2.y*sc, v2.z*sc, v2.w*sc};
    f16x8 H, L;
    #pragma unroll
    for (int jj = 0; jj < 8; ++jj) {
        _Float16 h = (_Float16)m[jj];
        H[jj] = h;
        L[jj] = (_Float16)(m[jj] - (float)h);
    }
    int b = row >> 12;         // row / 4096
    int tt = row & 4095;
    size_t dst = ((size_t)(b * TA + (tt >> 1))) * CN + lane * 8;
    if (tt & 1) { *(f16x8*)(Bhi + dst) = H; *(f16x8*)(Blo + dst) = L; }
    else        { *(f16x8*)(Ahi + dst) = H; *(f16x8*)(Alo + dst) = L; }
}

// ---------- kernel 2: init node keys (hi = ofloat(-inf), lo decodes to j=0)
__global__ void init_kernel(unsigned long long* __restrict__ nodekey) {
    int idx = blockIdx.x * 256 + threadIdx.x;
    if (idx < BN * TA)
        nodekey[idx] = (((unsigned long long)0x007FFFFFu) << 32) | 0xFFFFFFFFull;
}

// ---------- kernel 3: fp16-split MFMA score GEMM + fused row max/argmax ----
// grid (16 i-tiles, 16 j-tiles, 8 batches), 256 thr = 4 waves, 128x128 tile.
// global_load_lds staging (no VGPR round-trip); XOR-swizzled LDS layout via
// pre-swizzled global source + swizzled read (both sides, same involution).
__global__ __launch_bounds__(256, 3) void score_mfma_kernel(
        const _Float16* __restrict__ Ahi, const _Float16* __restrict__ Alo,
        const _Float16* __restrict__ Bhi, const _Float16* __restrict__ Blo,
        unsigned long long* __restrict__ nodekey) {
    __shared__ _Float16 lds[4 * 128 * KC];   // 4 planes x 128 rows x 32 halves = 32 KB
    const int b  = blockIdx.z;
    const int i0 = blockIdx.x * 128;
    const int j0 = blockIdx.y * 128;
    const int tid = threadIdx.x;
    const int lane = tid & 63;
    const int w = tid >> 6;
    const int wr = (w >> 1) * 64;
    const int wc = (w & 1) * 64;
    const size_t boff = (size_t)b * TA * CN;

    const _Float16* gbase[4] = {
        Ahi + boff + (size_t)i0 * CN,
        Alo + boff + (size_t)i0 * CN,
        Bhi + boff + (size_t)j0 * CN,
        Blo + boff + (size_t)j0 * CN };

    // staging source geometry (slot s = i*256 + tid; plane = i>>1)
    const int srow = tid >> 2;                       // 0..63 (plus 64 for odd i)
    const int segD = (tid & 3) ^ ((tid >> 3) & 3);   // data seg for swizzled slot

    f32x4 acc[4][4];
    #pragma unroll
    for (int m = 0; m < 4; ++m)
        #pragma unroll
        for (int n = 0; n < 4; ++n) acc[m][n] = (f32x4){0.f, 0.f, 0.f, 0.f};

    const int fr = lane & 15, ks = lane >> 4;
    // per-lane swizzled read offsets (k-invariant, hoisted)
    int aoff[4], boff2[4];
    #pragma unroll
    for (int m = 0; m < 4; ++m) {
        int r = wr + m * 16 + fr;
        aoff[m] = r * KC + (ks ^ ((r >> 1) & 3)) * 8;
    }
    #pragma unroll
    for (int n = 0; n < 4; ++n) {
        int r = wc + n * 16 + fr;
        boff2[n] = r * KC + (ks ^ ((r >> 1) & 3)) * 8;
    }

    for (int kt = 0; kt < CN; kt += KC) {
        // ---- stage 32 KB via 8 global_load_lds (16B/lane, linear LDS dest) ----
        #pragma unroll
        for (int i = 0; i < 8; ++i) {
            const _Float16* gp = gbase[i >> 1]
                + (size_t)((i & 1) * 64 + srow) * CN + kt + segD * 8;
            _Float16* lp = lds + i * 2048 + w * 512;
            __builtin_amdgcn_global_load_lds((g_u32_t*)gp, (lds_u32_t*)lp, 16, 0, 0);
        }
        __syncthreads();   // drains vmcnt -> staged data visible
        // ---- fragments + 48 MFMA ----
        f16x8 bh[4], bl[4];
        #pragma unroll
        for (int n = 0; n < 4; ++n) {
            bh[n] = *(const f16x8*)(&lds[2 * 4096 + boff2[n]]);
            bl[n] = *(const f16x8*)(&lds[3 * 4096 + boff2[n]]);
        }
        #pragma unroll
        for (int m = 0; m < 4; ++m) {
            f16x8 ah = *(const f16x8*)(&lds[0 * 4096 + aoff[m]]);
            f16x8 al = *(const f16x8*)(&lds[1 * 4096 + aoff[m]]);
            #pragma unroll
            for (int n = 0; n < 4; ++n) {
                acc[m][n] = __builtin_amdgcn_mfma_f32_16x16x32_f16(ah, bh[n], acc[m][n], 0, 0, 0);
                acc[m][n] = __builtin_amdgcn_mfma_f32_16x16x32_f16(ah, bl[n], acc[m][n], 0, 0, 0);
                acc[m][n] = __builtin_amdgcn_mfma_f32_16x16x32_f16(al, bh[n], acc[m][n], 0, 0, 0);
            }
        }
        __syncthreads();   // all waves done reading before next stage overwrites
    }

    // ---- epilogue: per-row max/argmax, C/D layout col=lane&15, row=(lane>>4)*4+reg
    const float SC = 1.0f / 1048576.0f;   // 2^-20
    #pragma unroll
    for (int m = 0; m < 4; ++m) {
        #pragma unroll
        for (int reg = 0; reg < 4; ++reg) {
            unsigned bhi = 0u, blo2 = 0u;
            #pragma unroll
            for (int n = 0; n < 4; ++n) {
                float sc = acc[m][n][reg] * SC;
                unsigned j = (unsigned)(j0 + wc + n * 16 + fr);
                unsigned khi = ofloat(sc), klo = 0xFFFFFFFFu - j;
                if (khi > bhi || (khi == bhi && klo > blo2)) { bhi = khi; blo2 = klo; }
            }
            #pragma unroll
            for (int mm2 = 8; mm2 > 0; mm2 >>= 1) {
                unsigned ohi = (unsigned)__shfl_xor((int)bhi, mm2, 16);
                unsigned olo = (unsigned)__shfl_xor((int)blo2, mm2, 16);
                if (ohi > bhi || (ohi == bhi && olo > blo2)) { bhi = ohi; blo2 = olo; }
            }
            if (fr == 0) {
                int i = i0 + wr + m * 16 + ks * 4 + reg;
                if (i != 0) {   // PROTECT_CLS: i==0 stays -inf
                    unsigned long long key = (((unsigned long long)bhi) << 32) | blo2;
                    atomicMax(&nodekey[b * TA + i], key);
                }
            }
        }
    }
}

// ---------- kernel 4: per-batch rank by counting (proven) ------------------
__global__ __launch_bounds__(1024) void rank_kernel(const unsigned long long* __restrict__ nodekey,
                                                    int* __restrict__ is_src,
                                                    int* __restrict__ unm_rank) {
    __shared__ unsigned long long K[2048];
    __shared__ unsigned char flag[2048];
    const int b = blockIdx.x;
    const int t = threadIdx.x;
    for (int i = t; i < 2048; i += 1024) {
        unsigned hi = (unsigned)(nodekey[b * TA + i] >> 32);
        K[i] = (((unsigned long long)hi) << 32) | (unsigned)(2047 - i);
    }
    __syncthreads();
    for (int i = t; i < 2048; i += 1024) {
        unsigned long long ki = K[i];
        int rank = 0;
        for (int j = 0; j < 2048; ++j) rank += (K[j] > ki) ? 1 : 0;
        flag[i] = (rank < RR) ? 1 : 0;
    }
    __syncthreads();
    for (int i = t; i < 2048; i += 1024) {
        int cnt = 0;
        for (int j = 0; j < i; ++j) cnt += flag[j] ? 0 : 1;
        is_src[b * TA + i] = flag[i];
        unm_rank[b * TA + i] = cnt;
    }
}

// ---------- kernel 5: copy unmerged + dst base rows (proven) ---------------
__global__ __launch_bounds__(128) void copy_kernel(const float* __restrict__ x,
                                                   const int* __restrict__ is_src,
                                                   const int* __restrict__ unm_rank,
                                                   float* __restrict__ out) {
    const int b = blockIdx.y;
    const int tt = blockIdx.x;
    const float* src;
    float* dst;
    if (tt < 2048) {
        int i = tt;
        if (is_src[b * TA + i]) return;
        src = x + ((size_t)b * TN + 2 * i) * CN;
        dst = out + ((size_t)b * MROWS + unm_rank[b * TA + i]) * CN;
    } else {
        int j = tt - 2048;
        src = x + ((size_t)b * TN + 2 * j + 1) * CN;
        dst = out + ((size_t)b * MROWS + BASEB + j) * CN;
    }
    ((float4*)dst)[threadIdx.x] = ((const float4*)src)[threadIdx.x];
}

// ---------- kernel 6: scatter-add merged sources (proven) ------------------
__global__ __launch_bounds__(256) void scatter_kernel(const float* __restrict__ x,
                                                      const int* __restrict__ is_src,
                                                      const unsigned long long* __restrict__ nodekey,
                                                      float* __restrict__ out) {
    const int b = blockIdx.y;
    const int i = blockIdx.x;
    if (!is_src[b * TA + i]) return;
    unsigned j = 0xFFFFFFFFu - (unsigned)(nodekey[b * TA + i] & 0xFFFFFFFFull);
    const float* src = x + ((size_t)b * TN + 2 * i) * CN;
    float* dst = out + ((size_t)b * MROWS + BASEB + j) * CN;
    for (int c = threadIdx.x; c < CN; c += 256) atomicAdd(&dst[c], src[c]);
}

// ---------- kernel 7: source_index (proven) --------------------------------
__global__ __launch_bounds__(256) void si_kernel(const int* __restrict__ is_src,
                                                 const int* __restrict__ unm_rank,
                                                 const unsigned long long* __restrict__ nodekey,
                                                 float* __restrict__ out_si) {
    int idx = blockIdx.x * 256 + threadIdx.x;
    if (idx >= BN * TN) return;
    int b = idx / TN, tt = idx % TN;
    int val;
    if (tt & 1) {
        val = BASEB + (tt >> 1);
    } else {
        int i = tt >> 1;
        if (is_src[b * TA + i]) {
            unsigned j = 0xFFFFFFFFu - (unsigned)(nodekey[b * TA + i] & 0xFFFFFFFFull);
            val = BASEB + (int)j;
        } else {
            val = unm_rank[b * TA + i];
        }
    }
    out_si[idx] = (float)val;
}

extern "C" void kernel_launch(void* const* d_in, const int* in_sizes, int n_in,
                              void* d_out, int out_size, void* d_ws, size_t ws_size,
                              hipStream_t stream) {
    const float* x = (const float*)d_in[0];
    const float* k = (const float*)d_in[1];
    float* out = (float*)d_out;
    float* out_si = out + (size_t)BN * MROWS * CN;

    char* ws = (char*)d_ws;
    const size_t PLANE = (size_t)BN * TA * CN;          // 8,388,608 elements
    _Float16* Ahi = (_Float16*)ws;
    _Float16* Alo = Ahi + PLANE;
    _Float16* Bhi = Alo + PLANE;
    _Float16* Blo = Bhi + PLANE;
    char* tail = ws + 4 * PLANE * sizeof(_Float16);     // 64 MB
    unsigned long long* nodekey = (unsigned long long*)(tail);
    int* is_src   = (int*)(tail + 128 * 1024);
    int* unm_rank = (int*)(tail + 192 * 1024);

    split_kernel<<<dim3(BN * TN / 4), dim3(256), 0, stream>>>(k, Ahi, Alo, Bhi, Blo);
    init_kernel<<<dim3((BN * TA + 255) / 256), dim3(256), 0, stream>>>(nodekey);
    score_mfma_kernel<<<dim3(16, 16, BN), dim3(256), 0, stream>>>(Ahi, Alo, Bhi, Blo, nodekey);
    rank_kernel<<<dim3(BN), dim3(1024), 0, stream>>>(nodekey, is_src, unm_rank);
    copy_kernel<<<dim3(4096, BN), dim3(128), 0, stream>>>(x, is_src, unm_rank, out);
    scatter_kernel<<<dim3(2048, BN), dim3(256), 0, stream>>>(x, is_src, nodekey, out);
    si_kernel<<<dim3((BN * TN + 255) / 256), dim3(256), 0, stream>>>(is_src, unm_rank, nodekey, out_si);
}

// Round 5
// 204.133 us; speedup vs baseline: 3.7140x; 1.9004x over previous
//
#include <hip/hip_runtime.h>
#include <stdint.h>

#define BN 8
#define TN 4096
#define CN 512
#define TA 2048
#define RR 1024
#define BASEB 1024
#define MROWS 3072
#define KC 32

typedef _Float16 f16x8 __attribute__((ext_vector_type(8)));
typedef float f32x4 __attribute__((ext_vector_type(4)));
typedef __attribute__((address_space(3))) uint32_t lds_u32_t;
typedef __attribute__((address_space(1))) const uint32_t g_u32_t;

__device__ __forceinline__ unsigned ofloat(float f) {
    unsigned u = __float_as_uint(f);
    return (u & 0x80000000u) ? ~u : (u | 0x80000000u);
}

// ---------- kernel 1: normalize rows of k, split into H(x2^10)/L fp16 planes,
// ---------- deinterleave even rows -> A planes, odd rows -> B planes
__global__ __launch_bounds__(256) void split_kernel(const float* __restrict__ k,
        _Float16* __restrict__ Ahi, _Float16* __restrict__ Alo,
        _Float16* __restrict__ Bhi, _Float16* __restrict__ Blo) {
    int row = blockIdx.x * 4 + (threadIdx.x >> 6);
    int lane = threadIdx.x & 63;
    const float* p = k + (size_t)row * CN;
    float4 v1 = *(const float4*)(p + lane * 8);
    float4 v2 = *(const float4*)(p + lane * 8 + 4);
    float s = v1.x*v1.x + v1.y*v1.y + v1.z*v1.z + v1.w*v1.w
            + v2.x*v2.x + v2.y*v2.y + v2.z*v2.z + v2.w*v2.w;
    #pragma unroll
    for (int off = 32; off > 0; off >>= 1) s += __shfl_xor(s, off);
    float sc = 1024.0f / (sqrtf(s) + 1e-12f);
    float m[8] = {v1.x*sc, v1.y*sc, v1.z*sc, v1.w*sc,
                  v2.x*sc, v2.y*sc, v2.z*sc, v2.w*sc};
    f16x8 H, L;
    #pragma unroll
    for (int jj = 0; jj < 8; ++jj) {
        _Float16 h = (_Float16)m[jj];
        H[jj] = h;
        L[jj] = (_Float16)(m[jj] - (float)h);
    }
    int b = row >> 12;         // row / 4096
    int tt = row & 4095;
    size_t dst = ((size_t)(b * TA + (tt >> 1))) * CN + lane * 8;
    if (tt & 1) { *(f16x8*)(Bhi + dst) = H; *(f16x8*)(Blo + dst) = L; }
    else        { *(f16x8*)(Ahi + dst) = H; *(f16x8*)(Alo + dst) = L; }
}

// ---------- kernel 2: init node keys (hi = ofloat(-inf), lo decodes to j=0)
__global__ void init_kernel(unsigned long long* __restrict__ nodekey) {
    int idx = blockIdx.x * 256 + threadIdx.x;
    if (idx < BN * TA)
        nodekey[idx] = (((unsigned long long)0x007FFFFFu) << 32) | 0xFFFFFFFFull;
}

// ---------- kernel 3: fp16-split MFMA score GEMM + fused row max/argmax ----
// grid (16 i-tiles, 16 j-tiles, 8 batches), 256 thr = 4 waves, 128x128 tile.
// global_load_lds staging (no VGPR round-trip); XOR-swizzled LDS layout via
// pre-swizzled global source + swizzled read (both sides, same involution).
__global__ __launch_bounds__(256, 3) void score_mfma_kernel(
        const _Float16* __restrict__ Ahi, const _Float16* __restrict__ Alo,
        const _Float16* __restrict__ Bhi, const _Float16* __restrict__ Blo,
        unsigned long long* __restrict__ nodekey) {
    __shared__ _Float16 lds[4 * 128 * KC];   // 4 planes x 128 rows x 32 halves = 32 KB
    const int b  = blockIdx.z;
    const int i0 = blockIdx.x * 128;
    const int j0 = blockIdx.y * 128;
    const int tid = threadIdx.x;
    const int lane = tid & 63;
    const int w = tid >> 6;
    const int wr = (w >> 1) * 64;
    const int wc = (w & 1) * 64;
    const size_t boff = (size_t)b * TA * CN;

    const _Float16* gbase[4] = {
        Ahi + boff + (size_t)i0 * CN,
        Alo + boff + (size_t)i0 * CN,
        Bhi + boff + (size_t)j0 * CN,
        Blo + boff + (size_t)j0 * CN };

    // staging source geometry (slot s = i*256 + tid; plane = i>>1)
    const int srow = tid >> 2;                       // 0..63 (plus 64 for odd i)
    const int segD = (tid & 3) ^ ((tid >> 3) & 3);   // data seg for swizzled slot

    f32x4 acc[4][4];
    #pragma unroll
    for (int m = 0; m < 4; ++m)
        #pragma unroll
        for (int n = 0; n < 4; ++n) acc[m][n] = (f32x4){0.f, 0.f, 0.f, 0.f};

    const int fr = lane & 15, ks = lane >> 4;
    // per-lane swizzled read offsets (k-invariant, hoisted)
    int aoff[4], boff2[4];
    #pragma unroll
    for (int m = 0; m < 4; ++m) {
        int r = wr + m * 16 + fr;
        aoff[m] = r * KC + (ks ^ ((r >> 1) & 3)) * 8;
    }
    #pragma unroll
    for (int n = 0; n < 4; ++n) {
        int r = wc + n * 16 + fr;
        boff2[n] = r * KC + (ks ^ ((r >> 1) & 3)) * 8;
    }

    for (int kt = 0; kt < CN; kt += KC) {
        // ---- stage 32 KB via 8 global_load_lds (16B/lane, linear LDS dest) ----
        #pragma unroll
        for (int i = 0; i < 8; ++i) {
            const _Float16* gp = gbase[i >> 1]
                + (size_t)((i & 1) * 64 + srow) * CN + kt + segD * 8;
            _Float16* lp = lds + i * 2048 + w * 512;
            __builtin_amdgcn_global_load_lds((g_u32_t*)gp, (lds_u32_t*)lp, 16, 0, 0);
        }
        __syncthreads();   // drains vmcnt -> staged data visible
        // ---- fragments + 48 MFMA ----
        f16x8 bh[4], bl[4];
        #pragma unroll
        for (int n = 0; n < 4; ++n) {
            bh[n] = *(const f16x8*)(&lds[2 * 4096 + boff2[n]]);
            bl[n] = *(const f16x8*)(&lds[3 * 4096 + boff2[n]]);
        }
        #pragma unroll
        for (int m = 0; m < 4; ++m) {
            f16x8 ah = *(const f16x8*)(&lds[0 * 4096 + aoff[m]]);
            f16x8 al = *(const f16x8*)(&lds[1 * 4096 + aoff[m]]);
            #pragma unroll
            for (int n = 0; n < 4; ++n) {
                acc[m][n] = __builtin_amdgcn_mfma_f32_16x16x32_f16(ah, bh[n], acc[m][n], 0, 0, 0);
                acc[m][n] = __builtin_amdgcn_mfma_f32_16x16x32_f16(ah, bl[n], acc[m][n], 0, 0, 0);
                acc[m][n] = __builtin_amdgcn_mfma_f32_16x16x32_f16(al, bh[n], acc[m][n], 0, 0, 0);
            }
        }
        __syncthreads();   // all waves done reading before next stage overwrites
    }

    // ---- epilogue: per-row max/argmax, C/D layout col=lane&15, row=(lane>>4)*4+reg
    const float SC = 1.0f / 1048576.0f;   // 2^-20
    #pragma unroll
    for (int m = 0; m < 4; ++m) {
        #pragma unroll
        for (int reg = 0; reg < 4; ++reg) {
            unsigned bhi = 0u, blo2 = 0u;
            #pragma unroll
            for (int n = 0; n < 4; ++n) {
                float sc = acc[m][n][reg] * SC;
                unsigned j = (unsigned)(j0 + wc + n * 16 + fr);
                unsigned khi = ofloat(sc), klo = 0xFFFFFFFFu - j;
                if (khi > bhi || (khi == bhi && klo > blo2)) { bhi = khi; blo2 = klo; }
            }
            #pragma unroll
            for (int mm2 = 8; mm2 > 0; mm2 >>= 1) {
                unsigned ohi = (unsigned)__shfl_xor((int)bhi, mm2, 16);
                unsigned olo = (unsigned)__shfl_xor((int)blo2, mm2, 16);
                if (ohi > bhi || (ohi == bhi && olo > blo2)) { bhi = ohi; blo2 = olo; }
            }
            if (fr == 0) {
                int i = i0 + wr + m * 16 + ks * 4 + reg;
                if (i != 0) {   // PROTECT_CLS: i==0 stays -inf
                    unsigned long long key = (((unsigned long long)bhi) << 32) | blo2;
                    atomicMax(&nodekey[b * TA + i], key);
                }
            }
        }
    }
}

// ---------- kernel 4a: parallel counting rank -> membership flag -----------
// grid (8 blocks, BN batches) x 256 thr; one thread ranks one node against
// the LDS-staged 2048 keys (same key/tiebreak semantics as the proven serial).
__global__ __launch_bounds__(256) void rank_flag_kernel(
        const unsigned long long* __restrict__ nodekey,
        int* __restrict__ is_src) {
    __shared__ unsigned long long K[2048];
    const int b = blockIdx.y;
    const int t = threadIdx.x;
    for (int i = t; i < 2048; i += 256) {
        unsigned hi = (unsigned)(nodekey[b * TA + i] >> 32);
        K[i] = (((unsigned long long)hi) << 32) | (unsigned)(2047 - i);
    }
    __syncthreads();
    const int i = blockIdx.x * 256 + t;
    const unsigned long long ki = K[i];
    int rank = 0;
    #pragma unroll 8
    for (int j = 0; j < 2048; ++j) rank += (K[j] > ki) ? 1 : 0;
    is_src[b * TA + i] = (rank < RR) ? 1 : 0;   // top-RR node_max are merged
}

// ---------- kernel 4b: per-batch exclusive rank of unmerged nodes ----------
// one block (1024 thr) per batch; Hillis-Steele inclusive scan over the
// complement flags (read-all -> barrier -> write-all per round: race-free).
__global__ __launch_bounds__(1024) void scan_kernel(const int* __restrict__ is_src,
                                                    int* __restrict__ unm_rank) {
    __shared__ int ps[2048];
    const int b = blockIdx.x;
    const int t = threadIdx.x;
    int f0 = 1 - is_src[b * TA + t];
    int f1 = 1 - is_src[b * TA + 1024 + t];
    ps[t] = f0;
    ps[t + 1024] = f1;
    __syncthreads();
    for (int off = 1; off < 2048; off <<= 1) {
        int v0 = (t >= off) ? ps[t - off] : 0;
        int v1 = ((t + 1024) >= off) ? ps[t + 1024 - off] : 0;
        __syncthreads();
        ps[t] += v0;
        ps[t + 1024] += v1;
        __syncthreads();
    }
    unm_rank[b * TA + t] = ps[t] - f0;                    // exclusive prefix
    unm_rank[b * TA + 1024 + t] = ps[t + 1024] - f1;
}

// ---------- kernel 5: copy unmerged + dst base rows (proven) ---------------
__global__ __launch_bounds__(128) void copy_kernel(const float* __restrict__ x,
                                                   const int* __restrict__ is_src,
                                                   const int* __restrict__ unm_rank,
                                                   float* __restrict__ out) {
    const int b = blockIdx.y;
    const int tt = blockIdx.x;
    const float* src;
    float* dst;
    if (tt < 2048) {
        int i = tt;
        if (is_src[b * TA + i]) return;
        src = x + ((size_t)b * TN + 2 * i) * CN;
        dst = out + ((size_t)b * MROWS + unm_rank[b * TA + i]) * CN;
    } else {
        int j = tt - 2048;
        src = x + ((size_t)b * TN + 2 * j + 1) * CN;
        dst = out + ((size_t)b * MROWS + BASEB + j) * CN;
    }
    ((float4*)dst)[threadIdx.x] = ((const float4*)src)[threadIdx.x];
}

// ---------- kernel 6: scatter-add merged sources (proven) ------------------
__global__ __launch_bounds__(256) void scatter_kernel(const float* __restrict__ x,
                                                      const int* __restrict__ is_src,
                                                      const unsigned long long* __restrict__ nodekey,
                                                      float* __restrict__ out) {
    const int b = blockIdx.y;
    const int i = blockIdx.x;
    if (!is_src[b * TA + i]) return;
    unsigned j = 0xFFFFFFFFu - (unsigned)(nodekey[b * TA + i] & 0xFFFFFFFFull);
    const float* src = x + ((size_t)b * TN + 2 * i) * CN;
    float* dst = out + ((size_t)b * MROWS + BASEB + j) * CN;
    for (int c = threadIdx.x; c < CN; c += 256) atomicAdd(&dst[c], src[c]);
}

// ---------- kernel 7: source_index (proven) --------------------------------
__global__ __launch_bounds__(256) void si_kernel(const int* __restrict__ is_src,
                                                 const int* __restrict__ unm_rank,
                                                 const unsigned long long* __restrict__ nodekey,
                                                 float* __restrict__ out_si) {
    int idx = blockIdx.x * 256 + threadIdx.x;
    if (idx >= BN * TN) return;
    int b = idx / TN, tt = idx % TN;
    int val;
    if (tt & 1) {
        val = BASEB + (tt >> 1);
    } else {
        int i = tt >> 1;
        if (is_src[b * TA + i]) {
            unsigned j = 0xFFFFFFFFu - (unsigned)(nodekey[b * TA + i] & 0xFFFFFFFFull);
            val = BASEB + (int)j;
        } else {
            val = unm_rank[b * TA + i];
        }
    }
    out_si[idx] = (float)val;
}

extern "C" void kernel_launch(void* const* d_in, const int* in_sizes, int n_in,
                              void* d_out, int out_size, void* d_ws, size_t ws_size,
                              hipStream_t stream) {
    const float* x = (const float*)d_in[0];
    const float* k = (const float*)d_in[1];
    float* out = (float*)d_out;
    float* out_si = out + (size_t)BN * MROWS * CN;

    char* ws = (char*)d_ws;
    const size_t PLANE = (size_t)BN * TA * CN;          // 8,388,608 elements
    _Float16* Ahi = (_Float16*)ws;
    _Float16* Alo = Ahi + PLANE;
    _Float16* Bhi = Alo + PLANE;
    _Float16* Blo = Bhi + PLANE;
    char* tail = ws + 4 * PLANE * sizeof(_Float16);     // 64 MB
    unsigned long long* nodekey = (unsigned long long*)(tail);
    int* is_src   = (int*)(tail + 128 * 1024);
    int* unm_rank = (int*)(tail + 192 * 1024);

    split_kernel<<<dim3(BN * TN / 4), dim3(256), 0, stream>>>(k, Ahi, Alo, Bhi, Blo);
    init_kernel<<<dim3((BN * TA + 255) / 256), dim3(256), 0, stream>>>(nodekey);
    score_mfma_kernel<<<dim3(16, 16, BN), dim3(256), 0, stream>>>(Ahi, Alo, Bhi, Blo, nodekey);
    rank_flag_kernel<<<dim3(8, BN), dim3(256), 0, stream>>>(nodekey, is_src);
    scan_kernel<<<dim3(BN), dim3(1024), 0, stream>>>(is_src, unm_rank);
    copy_kernel<<<dim3(4096, BN), dim3(128), 0, stream>>>(x, is_src, unm_rank, out);
    scatter_kernel<<<dim3(2048, BN), dim3(256), 0, stream>>>(x, is_src, nodekey, out);
    si_kernel<<<dim3((BN * TN + 255) / 256), dim3(256), 0, stream>>>(is_src, unm_rank, nodekey, out_si);
}